// Round 8
// baseline (174.975 us; speedup 1.0000x reference)
//
#include <hip/hip_runtime.h>

// RBFN fused: out = sqrt(1 + max(|x|^2+|c|^2-2 x.c, 0)) @ W
// R8: R6 structure (best: 512thr, 8 waves x 32 rows, NSB=16, 2 blocks/CU)
// + software-pipelined GEMM2: sPhi double-buffered, GEMM2(i-1) overlaps
// GEMM1(i) so the sqrt/pack/phi-write serial tail is off the critical path.

typedef __attribute__((ext_vector_type(8))) short bf16x8;
typedef __attribute__((ext_vector_type(4))) float f32x4;
typedef __attribute__((ext_vector_type(2))) unsigned int u32x2;
typedef __attribute__((ext_vector_type(4))) unsigned int u32x4;

#define N_FEAT 128
#define N_CENT 8192
#define N_ROWS 8192
#define L_OUT  64
#define LDK    136   // sStage row stride (shorts), 272B
#define LDC    40    // sPhi row stride (shorts), 80B
#define NSB    16    // centre splits: 32 row-blocks x 16 = 512 blocks = 2/CU
#define NCH    16    // 32-centre chunks per block
#define WS_ELEMS ((size_t)NSB * N_ROWS * L_OUT)          // fp32 partials
// aux region (bytes from aux base):
#define AUX_XBF   0                                       // 2MB
#define AUX_CBF   (AUX_XBF + N_ROWS * N_FEAT * 2)         // 2MB
#define AUX_WT    (AUX_CBF + N_CENT * N_FEAT * 2)         // 1MB
#define AUX_X2    (AUX_WT + L_OUT * N_CENT * 2)
#define AUX_C2    (AUX_X2 + N_ROWS * 4)
#define AUX_BYTES (AUX_C2 + N_CENT * 4)

__device__ __forceinline__ unsigned int pk2(float a, float b) {
    unsigned int ua = __builtin_bit_cast(unsigned int, a);
    unsigned int ub = __builtin_bit_cast(unsigned int, b);
    ua += 0x7FFFu + ((ua >> 16) & 1u);
    ub += 0x7FFFu + ((ub >> 16) & 1u);
    return (ua >> 16) | (ub & 0xFFFF0000u);
}

// ---- prep: xs -> xbf(-2x)+x2 ; centre -> cbf+(c2+1). 32 rows/block.
__global__ __launch_bounds__(256) void prep_xc(
    const float* __restrict__ xs, const float* __restrict__ centre,
    unsigned short* __restrict__ xbf, unsigned short* __restrict__ cbf,
    float* __restrict__ x2, float* __restrict__ c2p1) {
    const int isC = blockIdx.x >= 256;
    const int rb  = (blockIdx.x & 255) * 32;
    const int r   = threadIdx.x >> 3;
    const int g   = threadIdx.x & 7;
    const float* src = (isC ? centre : xs) + (size_t)(rb + r) * N_FEAT + g * 16;
    unsigned short* dst = (isC ? cbf : xbf) + (size_t)(rb + r) * N_FEAT + g * 16;
    const float sc = isC ? 1.0f : -2.0f;
    f32x4 t0 = *(const f32x4*)(src);
    f32x4 t1 = *(const f32x4*)(src + 4);
    f32x4 t2 = *(const f32x4*)(src + 8);
    f32x4 t3 = *(const f32x4*)(src + 12);
    float ss = t0.x*t0.x + t0.y*t0.y + t0.z*t0.z + t0.w*t0.w
             + t1.x*t1.x + t1.y*t1.y + t1.z*t1.z + t1.w*t1.w
             + t2.x*t2.x + t2.y*t2.y + t2.z*t2.z + t2.w*t2.w
             + t3.x*t3.x + t3.y*t3.y + t3.z*t3.z + t3.w*t3.w;
    u32x4 lo = { pk2(sc*t0.x, sc*t0.y), pk2(sc*t0.z, sc*t0.w),
                 pk2(sc*t1.x, sc*t1.y), pk2(sc*t1.z, sc*t1.w) };
    u32x4 hi = { pk2(sc*t2.x, sc*t2.y), pk2(sc*t2.z, sc*t2.w),
                 pk2(sc*t3.x, sc*t3.y), pk2(sc*t3.z, sc*t3.w) };
    *(u32x4*)(dst)     = lo;
    *(u32x4*)(dst + 8) = hi;
    ss += __shfl_xor(ss, 1);
    ss += __shfl_xor(ss, 2);
    ss += __shfl_xor(ss, 4);
    if (g == 0) {
        if (isC) c2p1[rb + r] = ss + 1.0f;
        else     x2[rb + r]   = ss;
    }
}

// ---- prep: W[8192][64] -> wT bf16 [64][8192]
__global__ __launch_bounds__(256) void prep_wt(
    const float* __restrict__ weight, unsigned short* __restrict__ wT) {
    const int n0 = blockIdx.x * 64;
    const int l  = threadIdx.x & 63;
    const int ng = (threadIdx.x >> 6) * 16;
    float v[16];
    #pragma unroll
    for (int i = 0; i < 16; ++i)
        v[i] = weight[(size_t)(n0 + ng + i) * L_OUT + l];
    u32x4 a = { pk2(v[0], v[1]),  pk2(v[2], v[3]),
                pk2(v[4], v[5]),  pk2(v[6], v[7]) };
    u32x4 b = { pk2(v[8], v[9]),  pk2(v[10], v[11]),
                pk2(v[12], v[13]), pk2(v[14], v[15]) };
    unsigned short* d = wT + (size_t)l * N_CENT + n0 + ng;
    *(u32x4*)(d)     = a;
    *(u32x4*)(d + 8) = b;
}

// MODE 0: partials to ws. MODE 1: atomicAdd into out.
template <int MODE>
__global__ __launch_bounds__(512, 4) void rbf_fused(
    const unsigned short* __restrict__ xbf, const unsigned short* __restrict__ cbf,
    const unsigned short* __restrict__ wT, const float* __restrict__ x2g,
    const float* __restrict__ c2g, float* __restrict__ dst) {

    __shared__ __align__(16) unsigned short sStage[2][32][LDK];
    __shared__ __align__(16) unsigned short sPhi[2][256][LDC];  // double-buffered
    __shared__ float sC2[2][32];

    const int tid  = threadIdx.x;
    const int w    = tid >> 6;        // 0..7
    const int lane = tid & 63;
    const int quad = lane >> 4;
    const int n16  = lane & 15;

    const int mb = blockIdx.x >> 4;
    const int sb = blockIdx.x & (NSB - 1);
    const int rowBase = mb * 256;
    const int chunk0  = sb * NCH;

    // ---- x fragments: direct 16B bf16 loads (B-operand layout) + x2
    bf16x8 aF[2][4];
    float  x2v[2];
    #pragma unroll
    for (int xt = 0; xt < 2; ++xt) {
        const int row = rowBase + 32 * w + xt * 16 + n16;
        const unsigned short* xr = xbf + (size_t)row * N_FEAT + quad * 8;
        #pragma unroll
        for (int kc = 0; kc < 4; ++kc)
            aF[xt][kc] = *(const bf16x8*)(xr + kc * 32);
        x2v[xt] = x2g[row];
    }

    f32x4 oAcc[2][4];
    #pragma unroll
    for (int xt = 0; xt < 2; ++xt)
        #pragma unroll
        for (int lt = 0; lt < 4; ++lt)
            oAcc[xt][lt] = (f32x4){0.f, 0.f, 0.f, 0.f};

    // staging roles: all 512 threads copy 16B of the centre chunk
    const int sr = tid >> 4;          // centre row 0..31
    const int sg = tid & 15;          // 8-short group

    u32x4 pcc;     // prefetched centre 16B
    float pc2;     // prefetched c2 (threads 0..31)

    auto loadChunk = [&](int c) {
        pcc = *(const u32x4*)(cbf + (size_t)(c * 32 + sr) * N_FEAT + sg * 8);
        if (tid < 32) pc2 = c2g[c * 32 + tid];
    };
    auto storeChunk = [&](int b) {
        *(u32x4*)&sStage[b][sr][sg * 8] = pcc;
        if (tid < 32) sC2[b][tid] = pc2;
    };

    loadChunk(chunk0);
    storeChunk(0);
    __syncthreads();

    bf16x8 wFa[4], wFb[4];   // W fragments ping-pong (chunk i / i-1)

    for (int ic = 0; ic < NCH; ++ic) {
        const int cur = ic & 1;
        const int n0  = (chunk0 + ic) * 32;
        if (ic < NCH - 1) loadChunk(chunk0 + ic + 1);

        // W fragments for this chunk: direct global->register (L2-hot)
        bf16x8* wFc = cur ? wFb : wFa;
        bf16x8* wFp = cur ? wFa : wFb;
        #pragma unroll
        for (int lt = 0; lt < 4; ++lt)
            wFc[lt] = *(const bf16x8*)(wT + (size_t)(lt * 16 + n16) * N_CENT
                                          + n0 + quad * 8);

        // GEMM1(i): S^T (m=centre, n=x) from sStage[cur]
        f32x4 sAcc[2][2];   // [ct][xt]
        #pragma unroll
        for (int ct = 0; ct < 2; ++ct)
            #pragma unroll
            for (int xt = 0; xt < 2; ++xt)
                sAcc[ct][xt] = (f32x4){0.f, 0.f, 0.f, 0.f};
        #pragma unroll
        for (int kc = 0; kc < 4; ++kc) {
            #pragma unroll
            for (int ct = 0; ct < 2; ++ct) {
                bf16x8 cA = *(const bf16x8*)&sStage[cur][ct * 16 + n16][kc * 32 + quad * 8];
                #pragma unroll
                for (int xt = 0; xt < 2; ++xt)
                    sAcc[ct][xt] = __builtin_amdgcn_mfma_f32_16x16x32_bf16(
                        cA, aF[xt][kc], sAcc[ct][xt], 0, 0, 0);
            }
        }

        // GEMM2(i-1): phi(i-1) @ W(i-1) -- independent of GEMM1(i); the
        // scheduler interleaves these MFMAs into GEMM1/sqrt latency.
        if (ic > 0) {
            bf16x8 pF[2];
            #pragma unroll
            for (int xt = 0; xt < 2; ++xt)
                pF[xt] = *(const bf16x8*)&sPhi[cur ^ 1][32 * w + xt * 16 + n16][quad * 8];
            #pragma unroll
            for (int lt = 0; lt < 4; ++lt)
                #pragma unroll
                for (int xt = 0; xt < 2; ++xt)
                    oAcc[xt][lt] = __builtin_amdgcn_mfma_f32_16x16x32_bf16(
                        pF[xt], wFp[lt], oAcc[xt][lt], 0, 0, 0);
        }

        // phi(i) = sqrt(max(dot + x2 + c2p1, 1)) -> sPhi[cur] (wave-private)
        #pragma unroll
        for (int ct = 0; ct < 2; ++ct) {
            f32x4 c2p1 = *(const f32x4*)&sC2[cur][ct * 16 + quad * 4];
            #pragma unroll
            for (int xt = 0; xt < 2; ++xt) {
                float ph[4];
                #pragma unroll
                for (int r = 0; r < 4; ++r) {
                    float t = sAcc[ct][xt][r] + x2v[xt] + c2p1[r];
                    ph[r] = __builtin_amdgcn_sqrtf(fmaxf(t, 1.0f));
                }
                u32x2 pk = { pk2(ph[0], ph[1]), pk2(ph[2], ph[3]) };
                *(u32x2*)&sPhi[cur][32 * w + xt * 16 + n16][ct * 16 + quad * 4] = pk;
            }
        }

        if (ic < NCH - 1) {
            storeChunk(cur ^ 1);
            __syncthreads();
        }
    }

    // drain: GEMM2 for the last chunk
    {
        const int last = (NCH - 1) & 1;
        bf16x8* wFp = last ? wFb : wFa;
        bf16x8 pF[2];
        #pragma unroll
        for (int xt = 0; xt < 2; ++xt)
            pF[xt] = *(const bf16x8*)&sPhi[last][32 * w + xt * 16 + n16][quad * 8];
        #pragma unroll
        for (int lt = 0; lt < 4; ++lt)
            #pragma unroll
            for (int xt = 0; xt < 2; ++xt)
                oAcc[xt][lt] = __builtin_amdgcn_mfma_f32_16x16x32_bf16(
                    pF[xt], wFp[lt], oAcc[xt][lt], 0, 0, 0);
    }

    // ---- epilogue
    if (MODE == 0) {
        float* ob = dst + ((size_t)sb * N_ROWS + rowBase + 32 * w) * L_OUT;
        #pragma unroll
        for (int xt = 0; xt < 2; ++xt)
            #pragma unroll
            for (int lt = 0; lt < 4; ++lt)
                #pragma unroll
                for (int r = 0; r < 4; ++r)
                    ob[(xt * 16 + quad * 4 + r) * L_OUT + lt * 16 + n16] =
                        oAcc[xt][lt][r];
    } else {
        float* ob = dst + (size_t)(rowBase + 32 * w) * L_OUT;
        #pragma unroll
        for (int xt = 0; xt < 2; ++xt)
            #pragma unroll
            for (int lt = 0; lt < 4; ++lt)
                #pragma unroll
                for (int r = 0; r < 4; ++r)
                    atomicAdd(&ob[(xt * 16 + quad * 4 + r) * L_OUT + lt * 16 + n16],
                              oAcc[xt][lt][r]);
    }
}

__global__ __launch_bounds__(256) void reduce_ws(const float* __restrict__ ws,
                                                float* __restrict__ out) {
    const size_t i = ((size_t)blockIdx.x * 256 + threadIdx.x) * 4;
    f32x4 s = (f32x4){0.f, 0.f, 0.f, 0.f};
    #pragma unroll
    for (int sb = 0; sb < NSB; ++sb)
        s += *(const f32x4*)(ws + (size_t)sb * N_ROWS * L_OUT + i);
    *(f32x4*)(out + i) = s;
}

extern "C" void kernel_launch(void* const* d_in, const int* in_sizes, int n_in,
                              void* d_out, int out_size, void* d_ws, size_t ws_size,
                              hipStream_t stream) {
    (void)in_sizes; (void)n_in; (void)out_size;
    const float* xs     = (const float*)d_in[0];
    const float* centre = (const float*)d_in[1];
    const float* weight = (const float*)d_in[2];
    float* out = (float*)d_out;

    const size_t needFull = WS_ELEMS * sizeof(float) + AUX_BYTES;
    const int mode0 = ws_size >= needFull;
    char* aux = (char*)d_ws + (mode0 ? WS_ELEMS * sizeof(float) : 0);
    unsigned short* xbf = (unsigned short*)(aux + AUX_XBF);
    unsigned short* cbf = (unsigned short*)(aux + AUX_CBF);
    unsigned short* wT  = (unsigned short*)(aux + AUX_WT);
    float* x2  = (float*)(aux + AUX_X2);
    float* c2  = (float*)(aux + AUX_C2);

    prep_xc<<<dim3(512), dim3(256), 0, stream>>>(xs, centre, xbf, cbf, x2, c2);
    prep_wt<<<dim3(N_CENT / 64), dim3(256), 0, stream>>>(weight, wT);

    if (mode0) {
        float* ws = (float*)d_ws;
        rbf_fused<0><<<dim3(32 * NSB), dim3(512), 0, stream>>>(xbf, cbf, wT, x2, c2, ws);
        reduce_ws<<<dim3(N_ROWS * L_OUT / 4 / 256), dim3(256), 0, stream>>>(ws, out);
    } else {
        hipMemsetAsync(d_out, 0, (size_t)N_ROWS * L_OUT * sizeof(float), stream);
        rbf_fused<1><<<dim3(32 * NSB), dim3(512), 0, stream>>>(xbf, cbf, wT, x2, c2, out);
    }
}

// Round 9
// 111.237 us; speedup vs baseline: 1.5730x; 1.5730x over previous
//
#include <hip/hip_runtime.h>

// RBFN fused: out = sqrt(1 + max(|x|^2+|c|^2-2 x.c, 0)) @ W
// R9: R8's cross-iteration pipeline (GEMM2(i-1) overlaps GEMM1(i)) but with
// NO runtime-selected register arrays (R8's spill cause): W(i-1) fragments
// are re-loaded from L2-resident wT each iteration instead of ping-ponged.

typedef __attribute__((ext_vector_type(8))) short bf16x8;
typedef __attribute__((ext_vector_type(4))) float f32x4;
typedef __attribute__((ext_vector_type(2))) unsigned int u32x2;
typedef __attribute__((ext_vector_type(4))) unsigned int u32x4;

#define N_FEAT 128
#define N_CENT 8192
#define N_ROWS 8192
#define L_OUT  64
#define LDK    136   // sStage row stride (shorts), 272B
#define LDC    40    // sPhi row stride (shorts), 80B
#define NSB    16    // centre splits: 32 row-blocks x 16 = 512 blocks = 2/CU
#define NCH    16    // 32-centre chunks per block
#define WS_ELEMS ((size_t)NSB * N_ROWS * L_OUT)          // fp32 partials
// aux region (bytes from aux base):
#define AUX_XBF   0                                       // 2MB
#define AUX_CBF   (AUX_XBF + N_ROWS * N_FEAT * 2)         // 2MB
#define AUX_WT    (AUX_CBF + N_CENT * N_FEAT * 2)         // 1MB
#define AUX_X2    (AUX_WT + L_OUT * N_CENT * 2)
#define AUX_C2    (AUX_X2 + N_ROWS * 4)
#define AUX_BYTES (AUX_C2 + N_CENT * 4)

__device__ __forceinline__ unsigned int pk2(float a, float b) {
    unsigned int ua = __builtin_bit_cast(unsigned int, a);
    unsigned int ub = __builtin_bit_cast(unsigned int, b);
    ua += 0x7FFFu + ((ua >> 16) & 1u);
    ub += 0x7FFFu + ((ub >> 16) & 1u);
    return (ua >> 16) | (ub & 0xFFFF0000u);
}

// ---- prep: xs -> xbf(-2x)+x2 ; centre -> cbf+(c2+1). 32 rows/block.
__global__ __launch_bounds__(256) void prep_xc(
    const float* __restrict__ xs, const float* __restrict__ centre,
    unsigned short* __restrict__ xbf, unsigned short* __restrict__ cbf,
    float* __restrict__ x2, float* __restrict__ c2p1) {
    const int isC = blockIdx.x >= 256;
    const int rb  = (blockIdx.x & 255) * 32;
    const int r   = threadIdx.x >> 3;
    const int g   = threadIdx.x & 7;
    const float* src = (isC ? centre : xs) + (size_t)(rb + r) * N_FEAT + g * 16;
    unsigned short* dst = (isC ? cbf : xbf) + (size_t)(rb + r) * N_FEAT + g * 16;
    const float sc = isC ? 1.0f : -2.0f;
    f32x4 t0 = *(const f32x4*)(src);
    f32x4 t1 = *(const f32x4*)(src + 4);
    f32x4 t2 = *(const f32x4*)(src + 8);
    f32x4 t3 = *(const f32x4*)(src + 12);
    float ss = t0.x*t0.x + t0.y*t0.y + t0.z*t0.z + t0.w*t0.w
             + t1.x*t1.x + t1.y*t1.y + t1.z*t1.z + t1.w*t1.w
             + t2.x*t2.x + t2.y*t2.y + t2.z*t2.z + t2.w*t2.w
             + t3.x*t3.x + t3.y*t3.y + t3.z*t3.z + t3.w*t3.w;
    u32x4 lo = { pk2(sc*t0.x, sc*t0.y), pk2(sc*t0.z, sc*t0.w),
                 pk2(sc*t1.x, sc*t1.y), pk2(sc*t1.z, sc*t1.w) };
    u32x4 hi = { pk2(sc*t2.x, sc*t2.y), pk2(sc*t2.z, sc*t2.w),
                 pk2(sc*t3.x, sc*t3.y), pk2(sc*t3.z, sc*t3.w) };
    *(u32x4*)(dst)     = lo;
    *(u32x4*)(dst + 8) = hi;
    ss += __shfl_xor(ss, 1);
    ss += __shfl_xor(ss, 2);
    ss += __shfl_xor(ss, 4);
    if (g == 0) {
        if (isC) c2p1[rb + r] = ss + 1.0f;
        else     x2[rb + r]   = ss;
    }
}

// ---- prep: W[8192][64] -> wT bf16 [64][8192]
__global__ __launch_bounds__(256) void prep_wt(
    const float* __restrict__ weight, unsigned short* __restrict__ wT) {
    const int n0 = blockIdx.x * 64;
    const int l  = threadIdx.x & 63;
    const int ng = (threadIdx.x >> 6) * 16;
    float v[16];
    #pragma unroll
    for (int i = 0; i < 16; ++i)
        v[i] = weight[(size_t)(n0 + ng + i) * L_OUT + l];
    u32x4 a = { pk2(v[0], v[1]),  pk2(v[2], v[3]),
                pk2(v[4], v[5]),  pk2(v[6], v[7]) };
    u32x4 b = { pk2(v[8], v[9]),  pk2(v[10], v[11]),
                pk2(v[12], v[13]), pk2(v[14], v[15]) };
    unsigned short* d = wT + (size_t)l * N_CENT + n0 + ng;
    *(u32x4*)(d)     = a;
    *(u32x4*)(d + 8) = b;
}

// MODE 0: partials to ws. MODE 1: atomicAdd into out.
template <int MODE>
__global__ __launch_bounds__(512, 4) void rbf_fused(
    const unsigned short* __restrict__ xbf, const unsigned short* __restrict__ cbf,
    const unsigned short* __restrict__ wT, const float* __restrict__ x2g,
    const float* __restrict__ c2g, float* __restrict__ dst) {

    __shared__ __align__(16) unsigned short sStage[2][32][LDK];
    __shared__ __align__(16) unsigned short sPhi[2][256][LDC];  // double-buffered
    __shared__ float sC2[2][32];

    const int tid  = threadIdx.x;
    const int w    = tid >> 6;        // 0..7
    const int lane = tid & 63;
    const int quad = lane >> 4;
    const int n16  = lane & 15;

    const int mb = blockIdx.x >> 4;
    const int sb = blockIdx.x & (NSB - 1);
    const int rowBase = mb * 256;
    const int chunk0  = sb * NCH;

    // ---- x fragments: direct 16B bf16 loads (B-operand layout) + x2
    bf16x8 aF[2][4];
    float  x2v[2];
    #pragma unroll
    for (int xt = 0; xt < 2; ++xt) {
        const int row = rowBase + 32 * w + xt * 16 + n16;
        const unsigned short* xr = xbf + (size_t)row * N_FEAT + quad * 8;
        #pragma unroll
        for (int kc = 0; kc < 4; ++kc)
            aF[xt][kc] = *(const bf16x8*)(xr + kc * 32);
        x2v[xt] = x2g[row];
    }

    f32x4 oAcc[2][4];
    #pragma unroll
    for (int xt = 0; xt < 2; ++xt)
        #pragma unroll
        for (int lt = 0; lt < 4; ++lt)
            oAcc[xt][lt] = (f32x4){0.f, 0.f, 0.f, 0.f};

    // staging roles: all 512 threads copy 16B of the centre chunk
    const int sr = tid >> 4;          // centre row 0..31
    const int sg = tid & 15;          // 8-short group

    u32x4 pcc;     // prefetched centre 16B
    float pc2;     // prefetched c2 (threads 0..31)

    auto loadChunk = [&](int c) {
        pcc = *(const u32x4*)(cbf + (size_t)(c * 32 + sr) * N_FEAT + sg * 8);
        if (tid < 32) pc2 = c2g[c * 32 + tid];
    };
    auto storeChunk = [&](int b) {
        *(u32x4*)&sStage[b][sr][sg * 8] = pcc;
        if (tid < 32) sC2[b][tid] = pc2;
    };

    loadChunk(chunk0);
    storeChunk(0);
    __syncthreads();

    // per-lane wT base: row (lt*16+n16), the n0/quad offset varies per iter
    const unsigned short* wRow = wT + n16 * N_CENT + quad * 8;

    for (int ic = 0; ic < NCH; ++ic) {
        const int cur = ic & 1;
        if (ic < NCH - 1) loadChunk(chunk0 + ic + 1);

        // W fragments for chunk i-1 (GEMM2's operand): L2-hot reload, no
        // register ping-pong -> all arrays statically indexed (no scratch).
        bf16x8 wFp[4];
        if (ic > 0) {
            const int n0p = (chunk0 + ic - 1) * 32;
            #pragma unroll
            for (int lt = 0; lt < 4; ++lt)
                wFp[lt] = *(const bf16x8*)(wRow + (size_t)lt * 16 * N_CENT + n0p);
        }

        // GEMM1(i): S^T (m=centre, n=x) from sStage[cur]
        f32x4 sAcc[2][2];   // [ct][xt]
        #pragma unroll
        for (int ct = 0; ct < 2; ++ct)
            #pragma unroll
            for (int xt = 0; xt < 2; ++xt)
                sAcc[ct][xt] = (f32x4){0.f, 0.f, 0.f, 0.f};
        #pragma unroll
        for (int kc = 0; kc < 4; ++kc) {
            #pragma unroll
            for (int ct = 0; ct < 2; ++ct) {
                bf16x8 cA = *(const bf16x8*)&sStage[cur][ct * 16 + n16][kc * 32 + quad * 8];
                #pragma unroll
                for (int xt = 0; xt < 2; ++xt)
                    sAcc[ct][xt] = __builtin_amdgcn_mfma_f32_16x16x32_bf16(
                        cA, aF[xt][kc], sAcc[ct][xt], 0, 0, 0);
            }
        }

        // GEMM2(i-1): phi(i-1) @ W(i-1) -- independent of GEMM1(i)
        if (ic > 0) {
            bf16x8 pF[2];
            #pragma unroll
            for (int xt = 0; xt < 2; ++xt)
                pF[xt] = *(const bf16x8*)&sPhi[cur ^ 1][32 * w + xt * 16 + n16][quad * 8];
            #pragma unroll
            for (int lt = 0; lt < 4; ++lt)
                #pragma unroll
                for (int xt = 0; xt < 2; ++xt)
                    oAcc[xt][lt] = __builtin_amdgcn_mfma_f32_16x16x32_bf16(
                        pF[xt], wFp[lt], oAcc[xt][lt], 0, 0, 0);
        }

        // phi(i) = sqrt(max(dot + x2 + c2p1, 1)) -> sPhi[cur] (wave-private)
        #pragma unroll
        for (int ct = 0; ct < 2; ++ct) {
            f32x4 c2p1 = *(const f32x4*)&sC2[cur][ct * 16 + quad * 4];
            #pragma unroll
            for (int xt = 0; xt < 2; ++xt) {
                float ph[4];
                #pragma unroll
                for (int r = 0; r < 4; ++r) {
                    float t = sAcc[ct][xt][r] + x2v[xt] + c2p1[r];
                    ph[r] = __builtin_amdgcn_sqrtf(fmaxf(t, 1.0f));
                }
                u32x2 pk = { pk2(ph[0], ph[1]), pk2(ph[2], ph[3]) };
                *(u32x2*)&sPhi[cur][32 * w + xt * 16 + n16][ct * 16 + quad * 4] = pk;
            }
        }

        if (ic < NCH - 1) {
            storeChunk(cur ^ 1);
            __syncthreads();
        }
    }

    // drain: GEMM2 for the last chunk
    {
        const int last = (NCH - 1) & 1;
        const int n0p  = (chunk0 + NCH - 1) * 32;
        bf16x8 wFp[4];
        #pragma unroll
        for (int lt = 0; lt < 4; ++lt)
            wFp[lt] = *(const bf16x8*)(wRow + (size_t)lt * 16 * N_CENT + n0p);
        bf16x8 pF[2];
        #pragma unroll
        for (int xt = 0; xt < 2; ++xt)
            pF[xt] = *(const bf16x8*)&sPhi[last][32 * w + xt * 16 + n16][quad * 8];
        #pragma unroll
        for (int lt = 0; lt < 4; ++lt)
            #pragma unroll
            for (int xt = 0; xt < 2; ++xt)
                oAcc[xt][lt] = __builtin_amdgcn_mfma_f32_16x16x32_bf16(
                    pF[xt], wFp[lt], oAcc[xt][lt], 0, 0, 0);
    }

    // ---- epilogue
    if (MODE == 0) {
        float* ob = dst + ((size_t)sb * N_ROWS + rowBase + 32 * w) * L_OUT;
        #pragma unroll
        for (int xt = 0; xt < 2; ++xt)
            #pragma unroll
            for (int lt = 0; lt < 4; ++lt)
                #pragma unroll
                for (int r = 0; r < 4; ++r)
                    ob[(xt * 16 + quad * 4 + r) * L_OUT + lt * 16 + n16] =
                        oAcc[xt][lt][r];
    } else {
        float* ob = dst + (size_t)(rowBase + 32 * w) * L_OUT;
        #pragma unroll
        for (int xt = 0; xt < 2; ++xt)
            #pragma unroll
            for (int lt = 0; lt < 4; ++lt)
                #pragma unroll
                for (int r = 0; r < 4; ++r)
                    atomicAdd(&ob[(xt * 16 + quad * 4 + r) * L_OUT + lt * 16 + n16],
                              oAcc[xt][lt][r]);
    }
}

__global__ __launch_bounds__(256) void reduce_ws(const float* __restrict__ ws,
                                                float* __restrict__ out) {
    const size_t i = ((size_t)blockIdx.x * 256 + threadIdx.x) * 4;
    f32x4 s = (f32x4){0.f, 0.f, 0.f, 0.f};
    #pragma unroll
    for (int sb = 0; sb < NSB; ++sb)
        s += *(const f32x4*)(ws + (size_t)sb * N_ROWS * L_OUT + i);
    *(f32x4*)(out + i) = s;
}

extern "C" void kernel_launch(void* const* d_in, const int* in_sizes, int n_in,
                              void* d_out, int out_size, void* d_ws, size_t ws_size,
                              hipStream_t stream) {
    (void)in_sizes; (void)n_in; (void)out_size;
    const float* xs     = (const float*)d_in[0];
    const float* centre = (const float*)d_in[1];
    const float* weight = (const float*)d_in[2];
    float* out = (float*)d_out;

    const size_t needFull = WS_ELEMS * sizeof(float) + AUX_BYTES;
    const int mode0 = ws_size >= needFull;
    char* aux = (char*)d_ws + (mode0 ? WS_ELEMS * sizeof(float) : 0);
    unsigned short* xbf = (unsigned short*)(aux + AUX_XBF);
    unsigned short* cbf = (unsigned short*)(aux + AUX_CBF);
    unsigned short* wT  = (unsigned short*)(aux + AUX_WT);
    float* x2  = (float*)(aux + AUX_X2);
    float* c2  = (float*)(aux + AUX_C2);

    prep_xc<<<dim3(512), dim3(256), 0, stream>>>(xs, centre, xbf, cbf, x2, c2);
    prep_wt<<<dim3(N_CENT / 64), dim3(256), 0, stream>>>(weight, wT);

    if (mode0) {
        float* ws = (float*)d_ws;
        rbf_fused<0><<<dim3(32 * NSB), dim3(512), 0, stream>>>(xbf, cbf, wT, x2, c2, ws);
        reduce_ws<<<dim3(N_ROWS * L_OUT / 4 / 256), dim3(256), 0, stream>>>(ws, out);
    } else {
        hipMemsetAsync(d_out, 0, (size_t)N_ROWS * L_OUT * sizeof(float), stream);
        rbf_fused<1><<<dim3(32 * NSB), dim3(512), 0, stream>>>(xbf, cbf, wT, x2, c2, out);
    }
}